// Round 5
// baseline (271.349 us; speedup 1.0000x reference)
//
#include <hip/hip_runtime.h>

// LinearAttention MI355X: B=2, C=96, N=131072 (x stored [B,C,N]), 8 heads x hd=12.
// 3 plain kernels (cross-block data crosses kernel boundaries only — no grid.sync):
//   k1 : weights fp32->fp16 + zero part                      (replaces memset+wcvt)
//   pA : 512 blocks x 4 tiles: k/v GEMMs -> ke,vl LDS -> context+S -> per-tile atomics
//   pC : 512 blocks: per-block Wproj fold (part->Mt in LDS), then 4 tiles:
//        q GEMM -> softmax -> out GEMM.  x loads software-pipelined in both pA/pC.
//
// Fragment layouts (gfx950, verified learn_hip m89/m118/m120):
//   A[m=lane&15][k=quad*8+j], B[k=quad*8+j][n=lane&15], C/D row=quad*4+reg col=lane&15

typedef _Float16 half_t;
typedef _Float16 half8 __attribute__((ext_vector_type(8)));
typedef float f32x4 __attribute__((ext_vector_type(4)));

#define MFMA16 __builtin_amdgcn_mfma_f32_16x16x32_f16
#define NSH 17
#define NP 16   // partial reduction buffers

// swizzled byte offset in a [row][128 halves] LDS tile (16B-block XOR keeps b128 alignment)
__device__ __forceinline__ int swz(int row, int colh) {
  return (row * 256 + colh * 2) ^ ((row & 7) << 4);
}

// ---------------- k1: weights fp32->fp16 + zero part ----------------
__global__ void k1(const float* __restrict__ Wq, const float* __restrict__ Wk,
                   const float* __restrict__ Wv, half_t* __restrict__ WqH,
                   half_t* __restrict__ WkH, half_t* __restrict__ WvH,
                   float* __restrict__ part) {
  const int g = blockIdx.x * 256 + threadIdx.x;   // 36*256 = 9216 exactly
  WqH[g] = (half_t)Wq[g];
  WkH[g] = (half_t)Wk[g];
  WvH[g] = (half_t)Wv[g];
  for (int i = g; i < NP * 2 * 1248; i += 9216) part[i] = 0.f;
}

// ---------------- pA: k,v GEMMs + context, 4 tiles/block, pipelined x ----------------
__global__ __launch_bounds__(256, 2)
void pA(const float* __restrict__ x, const half_t* __restrict__ WkH,
        const half_t* __restrict__ WvH, float* __restrict__ part) {
  // LDS: ke [96][128]h swz @0 (24576), vl @24576. total 49152
  __shared__ __align__(16) char smem[49152];

  const int tid  = threadIdx.x;
  const int lane = tid & 63, l15 = lane & 15, quad = lane >> 4, wid = tid >> 6;
  const int bid  = blockIdx.x;
  const int b    = bid >> 8;                       // 512 blocks: 0..255 b=0, 256..511 b=1
  const float* xbase = x + (((size_t)(b * 96 + quad * 8)) << NSH) + wid * 32 + l15;
  float* dst = part + (size_t)((bid & (NP - 1)) * 2 + b) * 1248;

  float xv[48];
  { // prefetch tile 0
    const float* xb = xbase + (((bid & 255) * 4 + 0) << 7);
#pragma unroll
    for (int ks = 0; ks < 3; ++ks)
#pragma unroll
      for (int j = 0; j < 8; ++j)
#pragma unroll
        for (int ct = 0; ct < 2; ++ct)
          xv[(ks * 8 + j) * 2 + ct] = xb[(((size_t)(ks * 32 + j)) << NSH) + ct * 16];
  }

#pragma unroll
  for (int tt = 0; tt < 4; ++tt) {
    // consume prefetched xv -> fp16 fragments
    half8 bf[3][2];
#pragma unroll
    for (int ks = 0; ks < 3; ++ks)
#pragma unroll
      for (int ct = 0; ct < 2; ++ct)
#pragma unroll
        for (int j = 0; j < 8; ++j)
          bf[ks][ct][j] = (half_t)xv[(ks * 8 + j) * 2 + ct];

    if (tt < 3) { // issue next tile's loads; latency hides under 2 GEMMs + context
      const float* xb = xbase + (((bid & 255) * 4 + tt + 1) << 7);
#pragma unroll
      for (int ks = 0; ks < 3; ++ks)
#pragma unroll
        for (int j = 0; j < 8; ++j)
#pragma unroll
          for (int ct = 0; ct < 2; ++ct)
            xv[(ks * 8 + j) * 2 + ct] = xb[(((size_t)(ks * 32 + j)) << NSH) + ct * 16];
    }

    f32x4 acc[6][2];
    // ---- k GEMM: D[c_out][n] ----
#pragma unroll
    for (int rt = 0; rt < 6; ++rt)
#pragma unroll
      for (int ct = 0; ct < 2; ++ct) acc[rt][ct] = (f32x4){0.f, 0.f, 0.f, 0.f};
#pragma unroll
    for (int ks = 0; ks < 3; ++ks) {
      half8 af[6];
#pragma unroll
      for (int rt = 0; rt < 6; ++rt)
        af[rt] = *(const half8*)&WkH[(rt * 16 + l15) * 96 + ks * 32 + quad * 8];
#pragma unroll
      for (int rt = 0; rt < 6; ++rt)
#pragma unroll
        for (int ct = 0; ct < 2; ++ct)
          acc[rt][ct] = MFMA16(af[rt], bf[ks][ct], acc[rt][ct], 0, 0, 0);
    }
    // exp epilogue -> ke (swizzled)
#pragma unroll
    for (int rt = 0; rt < 6; ++rt)
#pragma unroll
      for (int ct = 0; ct < 2; ++ct)
#pragma unroll
        for (int i = 0; i < 4; ++i) {
          int row = rt * 16 + quad * 4 + i;
          int col = (wid * 2 + ct) * 16 + l15;
          *(half_t*)(smem + swz(row, col)) = (half_t)__expf(acc[rt][ct][i]);
        }

    // ---- v GEMM ----
#pragma unroll
    for (int rt = 0; rt < 6; ++rt)
#pragma unroll
      for (int ct = 0; ct < 2; ++ct) acc[rt][ct] = (f32x4){0.f, 0.f, 0.f, 0.f};
#pragma unroll
    for (int ks = 0; ks < 3; ++ks) {
      half8 af[6];
#pragma unroll
      for (int rt = 0; rt < 6; ++rt)
        af[rt] = *(const half8*)&WvH[(rt * 16 + l15) * 96 + ks * 32 + quad * 8];
#pragma unroll
      for (int rt = 0; rt < 6; ++rt)
#pragma unroll
        for (int ct = 0; ct < 2; ++ct)
          acc[rt][ct] = MFMA16(af[rt], bf[ks][ct], acc[rt][ct], 0, 0, 0);
    }
#pragma unroll
    for (int rt = 0; rt < 6; ++rt)
#pragma unroll
      for (int ct = 0; ct < 2; ++ct)
#pragma unroll
        for (int i = 0; i < 4; ++i) {
          int row = rt * 16 + quad * 4 + i;
          int col = (wid * 2 + ct) * 16 + l15;
          *(half_t*)(smem + 24576 + swz(row, col)) = (half_t)acc[rt][ct][i];
        }
    __syncthreads();

    // ---- context MFMA (per-tile, round-1 numerics): wave wid -> heads 2w,2w+1 ----
#pragma unroll
    for (int hh = 0; hh < 2; ++hh) {
      const int h = wid * 2 + hh;
      int row = h * 12 + l15; row = row > 95 ? 95 : row;   // clamp, m>=12 discarded
      f32x4 c = (f32x4){0.f, 0.f, 0.f, 0.f};
#pragma unroll
      for (int ks = 0; ks < 4; ++ks) {
        const int off = swz(row, ks * 32 + quad * 8);
        half8 a  = *(const half8*)(smem + off);
        half8 bv = *(const half8*)(smem + 24576 + off);
        c = MFMA16(a, bv, c, 0, 0, 0);
      }
#pragma unroll
      for (int i = 0; i < 4; ++i) {
        int d = quad * 4 + i, e = l15;
        if (d < 12 && e < 12) atomicAdd(&dst[h * 144 + d * 12 + e], c[i]);
      }
    }
    // ---- S row sums (threads 0..95, per-tile atomic) ----
    if (tid < 96) {
      float s = 0.f;
#pragma unroll
      for (int j = 0; j < 16; ++j) {
        half8 v = *(const half8*)(smem + swz(tid, j * 8));
#pragma unroll
        for (int e = 0; e < 8; ++e) s += (float)v[e];
      }
      atomicAdd(&dst[1152 + tid], s);
    }
    __syncthreads();   // before next tile overwrites ke/vl
  }
}

// ---------------- pC: per-block Wproj fold + q GEMM + softmax + out GEMM ----------------
__global__ __launch_bounds__(256, 2)
void pC(const float* __restrict__ x, const half_t* __restrict__ WqH,
        const float* __restrict__ Wproj, const float* __restrict__ part,
        float* __restrict__ out) {
  // LDS: [0:19968) Mt_lds [96][104]h ; [20480: ...) ctxS 1248 f32 (transient, then qs)
  //      qs [128][128]h swz @20480 (32768).  total 53248
  __shared__ __align__(16) char smem[53248];
  half_t* Mt_lds = (half_t*)smem;
  float*  ctxS   = (float*)(smem + 20480);
  char*   qs     = smem + 20480;

  const int tid  = threadIdx.x;
  const int lane = tid & 63, l15 = lane & 15, quad = lane >> 4, wid = tid >> 6;
  const int bid  = blockIdx.x;
  const int b    = bid >> 8;
  const float* xbase = x + (((size_t)(b * 96 + quad * 8)) << NSH) + wid * 32 + l15;

  float xv[48];
  { // prefetch tile 0 FIRST — its latency hides under the Mt fold below
    const float* xb = xbase + (((bid & 255) * 4 + 0) << 7);
#pragma unroll
    for (int ks = 0; ks < 3; ++ks)
#pragma unroll
      for (int j = 0; j < 8; ++j)
#pragma unroll
        for (int ct = 0; ct < 2; ++ct)
          xv[(ks * 8 + j) * 2 + ct] = xb[(((size_t)(ks * 32 + j)) << NSH) + ct * 16];
  }

  // ---- B': reduce part over NP slots -> ctxS (LDS), then fold Wproj -> Mt_lds ----
  for (int idx = tid; idx < 1248; idx += 256) {
    float s = 0.f;
#pragma unroll
    for (int p = 0; p < NP; ++p) s += part[(size_t)(p * 2 + b) * 1248 + idx];
    ctxS[idx] = s;
  }
  __syncthreads();
#pragma unroll
  for (int i = 0; i < 36; ++i) {       // 36*256 = 9216 = 96*96 outputs
    int g = i * 256 + tid;
    int o = g / 96, r = g - o * 96;    // r = h*12+d
    int h = r / 12, d = r - h * 12;
    float s = ctxS[1152 + r];
    float acc = 0.f;
#pragma unroll
    for (int e = 0; e < 12; ++e)
      acc = fmaf(ctxS[h * 144 + d * 12 + e], Wproj[o * 96 + h * 12 + e], acc);
    Mt_lds[o * 104 + r] = (half_t)(acc / s);
  }
  __syncthreads();   // ctxS dead; qs region free

#pragma unroll
  for (int tt = 0; tt < 4; ++tt) {
    half8 bf[3][2];
#pragma unroll
    for (int ks = 0; ks < 3; ++ks)
#pragma unroll
      for (int ct = 0; ct < 2; ++ct)
#pragma unroll
        for (int j = 0; j < 8; ++j)
          bf[ks][ct][j] = (half_t)xv[(ks * 8 + j) * 2 + ct];

    if (tt < 3) { // issue next tile's loads; hide under q GEMM + softmax + out GEMM
      const float* xb = xbase + (((bid & 255) * 4 + tt + 1) << 7);
#pragma unroll
      for (int ks = 0; ks < 3; ++ks)
#pragma unroll
        for (int j = 0; j < 8; ++j)
#pragma unroll
          for (int ct = 0; ct < 2; ++ct)
            xv[(ks * 8 + j) * 2 + ct] = xb[(((size_t)(ks * 32 + j)) << NSH) + ct * 16];
    }

    const int n0 = (((bid & 255) * 4 + tt)) << 7;
    f32x4 acc[6][2];
    // ---- q GEMM ----
#pragma unroll
    for (int rt = 0; rt < 6; ++rt)
#pragma unroll
      for (int ct = 0; ct < 2; ++ct) acc[rt][ct] = (f32x4){0.f, 0.f, 0.f, 0.f};
#pragma unroll
    for (int ks = 0; ks < 3; ++ks) {
      half8 af[6];
#pragma unroll
      for (int rt = 0; rt < 6; ++rt)
        af[rt] = *(const half8*)&WqH[(rt * 16 + l15) * 96 + ks * 32 + quad * 8];
#pragma unroll
      for (int rt = 0; rt < 6; ++rt)
#pragma unroll
        for (int ct = 0; ct < 2; ++ct)
          acc[rt][ct] = MFMA16(af[rt], bf[ks][ct], acc[rt][ct], 0, 0, 0);
    }
    // q logits transposed into qs[token][ch] (swizzled)
#pragma unroll
    for (int rt = 0; rt < 6; ++rt)
#pragma unroll
      for (int ct = 0; ct < 2; ++ct)
#pragma unroll
        for (int i = 0; i < 4; ++i) {
          int row = rt * 16 + quad * 4 + i;           // channel
          int col = (wid * 2 + ct) * 16 + l15;        // token
          *(half_t*)(qs + swz(col, row)) = (half_t)acc[rt][ct][i];
        }
    __syncthreads();

    // softmax over head dim: thread owns (token n, head-group hg of 4 heads)
    {
      const int n = tid & 127, hg = tid >> 7;
      float q[48];
#pragma unroll
      for (int j = 0; j < 6; ++j) {
        half8 v = *(const half8*)(qs + swz(n, hg * 48 + j * 8));
#pragma unroll
        for (int e = 0; e < 8; ++e) q[j * 8 + e] = (float)v[e];
      }
#pragma unroll
      for (int hh = 0; hh < 4; ++hh) {
        float* ql = q + hh * 12;
        float m = ql[0];
#pragma unroll
        for (int j = 1; j < 12; ++j) m = fmaxf(m, ql[j]);
        float s = 0.f;
#pragma unroll
        for (int j = 0; j < 12; ++j) { ql[j] = __expf(ql[j] - m); s += ql[j]; }
        const float inv = 1.0f / s;
#pragma unroll
        for (int j = 0; j < 12; ++j) ql[j] *= inv;
      }
#pragma unroll
      for (int j = 0; j < 6; ++j) {
        half8 w;
#pragma unroll
        for (int e = 0; e < 8; ++e) w[e] = (half_t)q[j * 8 + e];
        *(half8*)(qs + swz(n, hg * 48 + j * 8)) = w;
      }
    }
    __syncthreads();

    // ---- out GEMM: D[o][n] = sum_r M[o][r]*q[r][n]; A from Mt_lds, B from qs ----
#pragma unroll
    for (int rt = 0; rt < 6; ++rt)
#pragma unroll
      for (int ct = 0; ct < 2; ++ct) acc[rt][ct] = (f32x4){0.f, 0.f, 0.f, 0.f};
#pragma unroll
    for (int ks = 0; ks < 3; ++ks) {
      half8 af[6], bq[2];
#pragma unroll
      for (int rt = 0; rt < 6; ++rt)
        af[rt] = *(const half8*)(smem + (rt * 16 + l15) * 208 + (ks * 32 + quad * 8) * 2);
#pragma unroll
      for (int ct = 0; ct < 2; ++ct)
        bq[ct] = *(const half8*)(qs + swz((wid * 2 + ct) * 16 + l15, ks * 32 + quad * 8));
#pragma unroll
      for (int rt = 0; rt < 6; ++rt)
#pragma unroll
        for (int ct = 0; ct < 2; ++ct)
          acc[rt][ct] = MFMA16(af[rt], bq[ct], acc[rt][ct], 0, 0, 0);
    }
#pragma unroll
    for (int rt = 0; rt < 6; ++rt)
#pragma unroll
      for (int ct = 0; ct < 2; ++ct)
#pragma unroll
        for (int i = 0; i < 4; ++i) {
          int row = rt * 16 + quad * 4 + i;
          int col = (wid * 2 + ct) * 16 + l15;
          out[(((size_t)(b * 96 + row)) << NSH) + n0 + col] = acc[rt][ct][i];
        }
    __syncthreads();   // before next tile overwrites qs
  }
}

extern "C" void kernel_launch(void* const* d_in, const int* in_sizes, int n_in,
                              void* d_out, int out_size, void* d_ws, size_t ws_size,
                              hipStream_t stream) {
  const float* x     = (const float*)d_in[0];
  const float* Wq    = (const float*)d_in[1];
  const float* Wk    = (const float*)d_in[2];
  const float* Wv    = (const float*)d_in[3];
  const float* Wproj = (const float*)d_in[4];
  float* out = (float*)d_out;
  float* ws  = (float*)d_ws;

  float*  part = ws;                               // 39936 f32
  half_t* WqH  = (half_t*)(ws + NP * 2 * 1248);    // 9216 h each
  half_t* WkH  = WqH + 9216;
  half_t* WvH  = WkH + 9216;

  k1<<<36, 256, 0, stream>>>(Wq, Wk, Wv, WqH, WkH, WvH, part);
  pA<<<512, 256, 0, stream>>>(x, WkH, WvH, part);
  pC<<<512, 256, 0, stream>>>(x, WqH, Wproj, part, out);
}